// Round 6
// baseline (1940.926 us; speedup 1.0000x reference)
//
#include <hip/hip_runtime.h>
#include <stdint.h>

#define TN_D 1024
#define TN_F 1024
#define SENT32 0xAAAAAAAAu
#define NBLK 64
#define CPB 16  // columns per block (1 per wave, 16 waves)

typedef _Float16 half4_t __attribute__((ext_vector_type(4)));

// ---------------------------------------------------------------------------
// Transpose + convert: core[s][i][j] f32 -> coreT[s][j][i] f16.
// ---------------------------------------------------------------------------
__global__ __launch_bounds__(256) void tn_transpose(const float* __restrict__ core,
                                                    _Float16* __restrict__ coreT) {
    __shared__ float tile[64][65];
    const int s = blockIdx.z;
    const size_t base = (size_t)s * TN_D * TN_D;
    const int j0 = blockIdx.x * 64;
    const int i0 = blockIdx.y * 64;
    const int tx = threadIdx.x;
    const int ty = threadIdx.y;
#pragma unroll
    for (int r = 0; r < 4; ++r) {
        const int ii = ty + 16 * r;
        const float4 v = *(const float4*)&core[base + (size_t)(i0 + ii) * TN_D + j0 + 4 * tx];
        tile[ii][4 * tx + 0] = v.x; tile[ii][4 * tx + 1] = v.y;
        tile[ii][4 * tx + 2] = v.z; tile[ii][4 * tx + 3] = v.w;
    }
    __syncthreads();
#pragma unroll
    for (int r = 0; r < 4; ++r) {
        const int jj = ty + 16 * r;
        _Float16 h4[4];
        h4[0] = (_Float16)tile[4 * tx + 0][jj];
        h4[1] = (_Float16)tile[4 * tx + 1][jj];
        h4[2] = (_Float16)tile[4 * tx + 2][jj];
        h4[3] = (_Float16)tile[4 * tx + 3][jj];
        *(uint64_t*)&coreT[base + (size_t)(j0 + jj) * TN_D + i0 + 4 * tx] = *(uint64_t*)h4;
    }
}

// Spin until dword at p != sentinel (0xAA poison; true values never match).
__device__ __forceinline__ float poll1(const uint32_t* p) {
    uint32_t u = __hip_atomic_load(p, __ATOMIC_RELAXED, __HIP_MEMORY_SCOPE_AGENT);
    while (u == SENT32)
        u = __hip_atomic_load(p, __ATOMIC_RELAXED, __HIP_MEMORY_SCOPE_AGENT);
    return __uint_as_float(u);
}

__device__ __forceinline__ float dot4h(float4 a, half4_t h) {
    return a.x * (float)h[0] + a.y * (float)h[1] + a.z * (float)h[2] + a.w * (float)h[3];
}

// ---------------------------------------------------------------------------
// Persistent chain, f16 matrix. 64 blocks x 1024 threads (16 waves); wave w
// owns column j = 16*blk + w. Per step (ONE barrier):
//   poll:    thread tid polls ONE dword of the previous v-row, writes it to
//            the step's lv buffer; barrier (v-ready).
//   dot:     wave w dots its register-prefetched f16 column vs lv with the
//            conflict-free b128 pattern (lane l owns {4l,256+4l,512+4l,768+4l};
//            R3/R5-measured 0 bank conflicts).
//   gather:  lane0 deposits into sentinel-guarded volatile redv[t&1][w];
//            wave0 spin-consumes deposits AS THEY APPEAR (R0-proven, ~140
//            ns/step cheaper than barrier+plain gather per R0/R5 A/B), then
//            issues ONE coalesced 64B agent store, THEN re-poisons (poison
//            moved off the publish path; depth-2 slots make this safe: any
//            deposit into slot t&1 for step t+2 is ordered after the v-ready
//            barrier of t+2, which wave0 reaches only after poisoning at t).
// lv is double-buffered: lv[(t+1)&1] writes race only with lv[t&1] readers.
// lv[t&1] rewrite at t+2 is gated: poll(t+1) cannot return before own-block
// store(t), which is after all step-t deposits, hence after all lv[t&1] reads.
// ---------------------------------------------------------------------------
__global__ __launch_bounds__(1024, 1) void tn_chain_f16(const int* __restrict__ x,
                                                        const _Float16* __restrict__ mat,
                                                        const float* __restrict__ left,
                                                        const float* __restrict__ right,
                                                        float* __restrict__ vg,
                                                        float* __restrict__ out) {
    __shared__ __align__(16) float lv[2][TN_D];   // 8 KB double-buffered v
    volatile __shared__ uint32_t redv[2][CPB];    // ping-pong deposit slots
    __shared__ int xs[TN_F];                      // 4 KB symbol stream
    __shared__ float red2[CPB];

    const int tid = threadIdx.x;
    const int w = tid >> 6;
    const int l = tid & 63;
    const int j = blockIdx.x * CPB + w;

    xs[tid] = x[tid];
    if (tid < 2 * CPB) ((volatile uint32_t*)redv)[tid] = SENT32;
    __syncthreads();

    half4_t A0, A1, A2, A3, B0, B1, B2, B3;
    {
        const half4_t* cp = (const half4_t*)(mat + ((size_t)xs[0] * TN_D + j) * TN_D);
        A0 = cp[l]; A1 = cp[64 + l]; A2 = cp[128 + l]; A3 = cp[192 + l];
    }

    for (int t = 0; t < TN_F; t += 2) {
        const int s1 = xs[t + 1];
        const int s2 = xs[(t + 2 < TN_F) ? t + 2 : TN_F - 1];

        // ================= even step t (buffer 0, regs A, slot 0) =================
        if (t == 0) lv[0][tid] = left[tid];
        else        lv[0][tid] = poll1((const uint32_t*)vg + (size_t)(t - 1) * TN_D + tid);
        __syncthreads();  // v ready
        {   // prefetch col for t+1 (drained at first use, a step away)
            const half4_t* cp = (const half4_t*)(mat + ((size_t)s1 * TN_D + j) * TN_D);
            B0 = cp[l]; B1 = cp[64 + l]; B2 = cp[128 + l]; B3 = cp[192 + l];
        }
        {
            const float4* vv = (const float4*)lv[0];
            float acc = dot4h(vv[l], A0) + dot4h(vv[64 + l], A1) +
                        dot4h(vv[128 + l], A2) + dot4h(vv[192 + l], A3);
#pragma unroll
            for (int off = 32; off; off >>= 1) acc += __shfl_down(acc, off, 64);
            if (l == 0) {
                __asm__ volatile("" ::: "memory");
                redv[0][w] = __float_as_uint(acc);
            }
            if (w == 0 && l < CPB) {
                uint32_t u = redv[0][l];
                while (u == SENT32) u = redv[0][l];
                __hip_atomic_store((uint32_t*)vg + (size_t)t * TN_D + blockIdx.x * CPB + l,
                                   u, __ATOMIC_RELAXED, __HIP_MEMORY_SCOPE_AGENT);
                redv[0][l] = SENT32;  // re-poison AFTER publish (off critical path)
            }
        }

        // ================= odd step t+1 (buffer 1, regs B, slot 1) =================
        lv[1][tid] = poll1((const uint32_t*)vg + (size_t)t * TN_D + tid);
        __syncthreads();  // v ready
        {   // prefetch col for t+2
            const half4_t* cp = (const half4_t*)(mat + ((size_t)s2 * TN_D + j) * TN_D);
            A0 = cp[l]; A1 = cp[64 + l]; A2 = cp[128 + l]; A3 = cp[192 + l];
        }
        {
            const float4* vv = (const float4*)lv[1];
            float acc = dot4h(vv[l], B0) + dot4h(vv[64 + l], B1) +
                        dot4h(vv[128 + l], B2) + dot4h(vv[192 + l], B3);
#pragma unroll
            for (int off = 32; off; off >>= 1) acc += __shfl_down(acc, off, 64);
            if (l == 0) {
                __asm__ volatile("" ::: "memory");
                redv[1][w] = __float_as_uint(acc);
            }
            if (w == 0 && l < CPB) {
                uint32_t u = redv[1][l];
                while (u == SENT32) u = redv[1][l];
                __hip_atomic_store((uint32_t*)vg + (size_t)(t + 1) * TN_D + blockIdx.x * CPB + l,
                                   u, __ATOMIC_RELAXED, __HIP_MEMORY_SCOPE_AGENT);
                redv[1][l] = SENT32;
            }
        }
    }

    // ---- final dot with right boundary: block 0 ----
    if (blockIdx.x == 0) {
        float v = poll1((const uint32_t*)vg + (size_t)(TN_F - 1) * TN_D + tid);
        float p = v * right[tid];
#pragma unroll
        for (int off = 32; off; off >>= 1) p += __shfl_down(p, off, 64);
        if (l == 0) red2[w] = p;
        __syncthreads();
        if (tid == 0) {
            float s = 0.f;
#pragma unroll
            for (int k = 0; k < CPB; ++k) s += red2[k];
            out[0] = s;
        }
    }
}

// ---------------------------------------------------------------------------
// Fallback (tiny workspace): R2-structure fp32, no transpose.
// ---------------------------------------------------------------------------
__device__ __forceinline__ float4 poll4(const uint32_t* vp) {
    const unsigned long long* p = (const unsigned long long*)vp;
    unsigned long long a = __hip_atomic_load(p, __ATOMIC_RELAXED, __HIP_MEMORY_SCOPE_AGENT);
    unsigned long long b = __hip_atomic_load(p + 1, __ATOMIC_RELAXED, __HIP_MEMORY_SCOPE_AGENT);
    while ((uint32_t)a == SENT32 || (uint32_t)(a >> 32) == SENT32)
        a = __hip_atomic_load(p, __ATOMIC_RELAXED, __HIP_MEMORY_SCOPE_AGENT);
    while ((uint32_t)b == SENT32 || (uint32_t)(b >> 32) == SENT32)
        b = __hip_atomic_load(p + 1, __ATOMIC_RELAXED, __HIP_MEMORY_SCOPE_AGENT);
    return make_float4(__uint_as_float((uint32_t)a), __uint_as_float((uint32_t)(a >> 32)),
                       __uint_as_float((uint32_t)b), __uint_as_float((uint32_t)(b >> 32)));
}

__global__ __launch_bounds__(256, 1) void tn_chain_f32(const int* __restrict__ x,
                                                       const float* __restrict__ mat,
                                                       const float* __restrict__ left,
                                                       const float* __restrict__ right,
                                                       float* __restrict__ vg,
                                                       float* __restrict__ out) {
    __shared__ float4 lv[2][TN_D / 4];
    __shared__ float red[4];
    const int tid = threadIdx.x;
    const int w = tid >> 6;
    const int l = tid & 63;
    const int j = blockIdx.x * 4 + w;

    for (int t = 0; t < TN_F; ++t) {
        if (t == 0) lv[0][tid] = ((const float4*)left)[tid];
        else lv[t & 1][tid] = poll4((const uint32_t*)vg + (size_t)(t - 1) * TN_D + 4 * tid);
        __syncthreads();
        const float* mp = mat + (size_t)x[t] * TN_D * TN_D + j;
        const float4* vv = lv[t & 1];
        float acc = 0.f;
#pragma unroll
        for (int k = 0; k < 4; ++k) {
            const int i = 4 * l + 256 * k;
            const float4 v = vv[l + 64 * k];
            acc += v.x * mp[(size_t)i * TN_D] + v.y * mp[(size_t)(i + 1) * TN_D] +
                   v.z * mp[(size_t)(i + 2) * TN_D] + v.w * mp[(size_t)(i + 3) * TN_D];
        }
#pragma unroll
        for (int off = 32; off; off >>= 1) acc += __shfl_down(acc, off, 64);
        if (l == 0)
            __hip_atomic_store((uint32_t*)vg + (size_t)t * TN_D + j, __float_as_uint(acc),
                               __ATOMIC_RELAXED, __HIP_MEMORY_SCOPE_AGENT);
    }
    if (blockIdx.x == 0) {
        float4 v = poll4((const uint32_t*)vg + (size_t)(TN_F - 1) * TN_D + 4 * tid);
        const float4 r4 = ((const float4*)right)[tid];
        float p = v.x * r4.x + v.y * r4.y + v.z * r4.z + v.w * r4.w;
#pragma unroll
        for (int off = 32; off; off >>= 1) p += __shfl_down(p, off, 64);
        if (l == 0) red[w] = p;
        __syncthreads();
        if (tid == 0) out[0] = red[0] + red[1] + red[2] + red[3];
    }
}

extern "C" void kernel_launch(void* const* d_in, const int* in_sizes, int n_in,
                              void* d_out, int out_size, void* d_ws, size_t ws_size,
                              hipStream_t stream) {
    const int* x = (const int*)d_in[0];
    const float* core = (const float*)d_in[1];
    const float* left = (const float*)d_in[2];
    const float* right = (const float*)d_in[3];
    float* out = (float*)d_out;

    const int nsym = in_sizes[1] / (TN_D * TN_D);
    const size_t coreTBytes = (size_t)in_sizes[1] * sizeof(_Float16);  // 64 MB
    const size_t vbufBytes = (size_t)TN_F * TN_D * sizeof(float);      // 4 MB

    if (ws_size >= coreTBytes + vbufBytes) {
        _Float16* coreT = (_Float16*)d_ws;
        float* vg = (float*)((char*)d_ws + coreTBytes);
        hipMemsetAsync(vg, 0xAA, vbufBytes, stream);
        tn_transpose<<<dim3(16, 16, nsym), dim3(16, 16), 0, stream>>>(core, coreT);
        tn_chain_f16<<<NBLK, 1024, 0, stream>>>(x, coreT, left, right, vg, out);
    } else {
        float* vg = (float*)d_ws;
        hipMemsetAsync(vg, 0xAA, vbufBytes, stream);
        tn_chain_f32<<<256, 256, 0, stream>>>(x, core, left, right, vg, out);
    }
}